// Round 1
// baseline (3558.148 us; speedup 1.0000x reference)
//
#include <hip/hip_runtime.h>

// ---------------------------------------------------------------------------
// SharedOnlyMLP: out = (silu(x@(gw*gs).T) * (x@(uw*us).T)) @ (dw*ds).T
// x:[8192,4096] f32, gw/uw:[11008,4096] i32(int8 vals), dw:[4096,11008] i32,
// scales per out-row. Strategy: dequant weights -> bf16 (scales folded),
// x -> bf16, three 128^2-tile bf16 MFMA GEMMs (B^T layout), SiLU fused into
// the "up" GEMM epilogue. fp32 output.
// ---------------------------------------------------------------------------

typedef __attribute__((ext_vector_type(8))) __bf16 bf16x8;
typedef __attribute__((ext_vector_type(4))) float f32x4;
typedef __attribute__((ext_vector_type(8))) unsigned short ushort8;

#define D_MODEL 4096
#define D_FF    11008
#define NTOK    8192

__device__ __forceinline__ unsigned short f32_to_bf16(float f) {
    union { float f; unsigned u; } v; v.f = f;
    unsigned r = v.u + 0x7fffu + ((v.u >> 16) & 1u);   // round-nearest-even
    return (unsigned short)(r >> 16);
}
__device__ __forceinline__ float bf16_to_f32(unsigned short s) {
    union { unsigned u; float f; } v; v.u = ((unsigned)s) << 16;
    return v.f;
}

__device__ __forceinline__ void gload_lds16(const void* g, void* l) {
    __builtin_amdgcn_global_load_lds(
        (const __attribute__((address_space(1))) void*)g,
        (__attribute__((address_space(3))) void*)l, 16, 0, 0);
}

// ---- weight dequant: int32 (int8 values) * s[row] -> bf16, 8 elems/thread ----
__global__ __launch_bounds__(256)
void dequant_w_kernel(const int* __restrict__ w, const float* __restrict__ s,
                      unsigned short* __restrict__ out, int cols, long long total)
{
    long long i = ((long long)blockIdx.x * 256 + threadIdx.x) * 8;
    if (i >= total) return;
    float sc = s[(int)(i / cols)];        // 8-elem group never crosses a row (cols % 8 == 0)
    int4 w0 = *(const int4*)(w + i);
    int4 w1 = *(const int4*)(w + i + 4);
    ushort8 r;
    r[0] = f32_to_bf16((float)w0.x * sc);
    r[1] = f32_to_bf16((float)w0.y * sc);
    r[2] = f32_to_bf16((float)w0.z * sc);
    r[3] = f32_to_bf16((float)w0.w * sc);
    r[4] = f32_to_bf16((float)w1.x * sc);
    r[5] = f32_to_bf16((float)w1.y * sc);
    r[6] = f32_to_bf16((float)w1.z * sc);
    r[7] = f32_to_bf16((float)w1.w * sc);
    *(ushort8*)(out + i) = r;
}

// ---- x: f32 -> bf16, 8 elems/thread ----
__global__ __launch_bounds__(256)
void cvt_x_kernel(const float* __restrict__ x, unsigned short* __restrict__ out,
                  long long total)
{
    long long i = ((long long)blockIdx.x * 256 + threadIdx.x) * 8;
    if (i >= total) return;
    float4 a = *(const float4*)(x + i);
    float4 b = *(const float4*)(x + i + 4);
    ushort8 r;
    r[0] = f32_to_bf16(a.x); r[1] = f32_to_bf16(a.y);
    r[2] = f32_to_bf16(a.z); r[3] = f32_to_bf16(a.w);
    r[4] = f32_to_bf16(b.x); r[5] = f32_to_bf16(b.y);
    r[6] = f32_to_bf16(b.z); r[7] = f32_to_bf16(b.w);
    *(ushort8*)(out + i) = r;
}

// ---------------------------------------------------------------------------
// GEMM: C[M][N] = A[M][K] @ B[N][K]^T  (B^T layout: row n of B = column n)
// 128x128 tile, BK=32, 256 threads (4 waves, 2x2), 4x4 frags of 16x16x32 MFMA.
// m97 structure: global_load_lds width-16 staging, 2 barriers per K-step.
// MODE 0: store bf16. MODE 1: h = silu(gate)*acc -> bf16 (in-place ok).
// MODE 2: store f32.
// ---------------------------------------------------------------------------
template<int MODE>
__global__ __launch_bounds__(256)
void gemm_bt(const unsigned short* __restrict__ A,
             const unsigned short* __restrict__ B,
             void* __restrict__ C,
             const unsigned short* __restrict__ gateb,
             int M, int N, int K)
{
    __shared__ unsigned short lds_a[128 * 32];
    __shared__ unsigned short lds_b[128 * 32];

    const int tid  = threadIdx.x;
    const int lane = tid & 63;
    const int wave = tid >> 6;

    // XCD-aware swizzle (nwg % 8 == 0 for all our launches -> bijective)
    const int nbx = gridDim.x;
    int orig = blockIdx.y * nbx + blockIdx.x;
    int nwg  = nbx * gridDim.y;
    int cpx  = nwg >> 3;
    int swz  = (orig & 7) * cpx + (orig >> 3);
    const int bn = swz % nbx;
    const int bm = swz / nbx;

    const int m0 = bm * 128, n0 = bn * 128;
    const int wm = wave >> 1, wn = wave & 1;

    // staging: chunk c = wave (+4). lane l -> row c*16 + l/4, col (l&3)*8
    const int st_row = lane >> 2;
    const int st_col = (lane & 3) * 8;

    const unsigned short* a0 = A + (size_t)(m0 + wave * 16 + st_row) * K + st_col;
    const unsigned short* b0 = B + (size_t)(n0 + wave * 16 + st_row) * K + st_col;
    const unsigned short* a1 = a0 + (size_t)64 * K;
    const unsigned short* b1 = b0 + (size_t)64 * K;

    unsigned short* la0 = &lds_a[wave * 512];
    unsigned short* la1 = &lds_a[(wave + 4) * 512];
    unsigned short* lb0 = &lds_b[wave * 512];
    unsigned short* lb1 = &lds_b[(wave + 4) * 512];

    // fragment addressing: row = l&15, k = (l>>4)*8 .. +8 (contiguous octet)
    const int fr = lane & 15;
    const int fk = (lane >> 4) * 8;

    f32x4 acc[4][4] = {};

    for (int k0 = 0; k0 < K; k0 += 32) {
        gload_lds16(a0, la0);
        gload_lds16(a1, la1);
        gload_lds16(b0, lb0);
        gload_lds16(b1, lb1);
        a0 += 32; a1 += 32; b0 += 32; b1 += 32;
        __syncthreads();                       // vmcnt(0) + barrier

        bf16x8 af[4], bfv[4];
        #pragma unroll
        for (int mi = 0; mi < 4; ++mi)
            af[mi] = *(const bf16x8*)&lds_a[(wm * 64 + mi * 16 + fr) * 32 + fk];
        #pragma unroll
        for (int ni = 0; ni < 4; ++ni)
            bfv[ni] = *(const bf16x8*)&lds_b[(wn * 64 + ni * 16 + fr) * 32 + fk];

        #pragma unroll
        for (int mi = 0; mi < 4; ++mi)
            #pragma unroll
            for (int ni = 0; ni < 4; ++ni)
                acc[mi][ni] = __builtin_amdgcn_mfma_f32_16x16x32_bf16(
                    af[mi], bfv[ni], acc[mi][ni], 0, 0, 0);

        __syncthreads();                       // protect LDS before next stage
    }

    // epilogue: D row = (l>>4)*4 + q, col = l&15  (m89-verified C/D layout)
    const int er = (lane >> 4) * 4;
    const int ec = lane & 15;
    #pragma unroll
    for (int mi = 0; mi < 4; ++mi) {
        #pragma unroll
        for (int ni = 0; ni < 4; ++ni) {
            #pragma unroll
            for (int q = 0; q < 4; ++q) {
                int row = m0 + wm * 64 + mi * 16 + er + q;
                int col = n0 + wn * 64 + ni * 16 + ec;
                size_t idx = (size_t)row * N + col;
                float v = acc[mi][ni][q];
                if (MODE == 0) {
                    ((unsigned short*)C)[idx] = f32_to_bf16(v);
                } else if (MODE == 1) {
                    float g   = bf16_to_f32(gateb[idx]);
                    float sig = 1.0f / (1.0f + __expf(-g));
                    ((unsigned short*)C)[idx] = f32_to_bf16(g * sig * v);
                } else {
                    ((float*)C)[idx] = v;
                }
            }
        }
    }
}

extern "C" void kernel_launch(void* const* d_in, const int* in_sizes, int n_in,
                              void* d_out, int out_size, void* d_ws, size_t ws_size,
                              hipStream_t stream)
{
    const float* x  = (const float*)d_in[0];
    const int*   gw = (const int*)  d_in[1];
    const float* gs = (const float*)d_in[2];
    const int*   uw = (const int*)  d_in[3];
    const float* us = (const float*)d_in[4];
    const int*   dw = (const int*)  d_in[5];
    const float* dsc= (const float*)d_in[6];

    // workspace layout (518 MB total)
    char* ws = (char*)d_ws;
    unsigned short* Xb = (unsigned short*)ws;  ws += (size_t)NTOK  * D_MODEL * 2;
    unsigned short* Wg = (unsigned short*)ws;  ws += (size_t)D_FF  * D_MODEL * 2;
    unsigned short* Wu = (unsigned short*)ws;  ws += (size_t)D_FF  * D_MODEL * 2;
    unsigned short* Wd = (unsigned short*)ws;  ws += (size_t)D_MODEL * D_FF * 2;
    unsigned short* H  = (unsigned short*)ws;  // NTOK * D_FF bf16 (gate, then h)

    const long long wtot = (long long)D_FF * D_MODEL;     // 45,088,768 (%2048==0)
    const long long xtot = (long long)NTOK * D_MODEL;     // 33,554,432 (%2048==0)

    dequant_w_kernel<<<(int)(wtot / 2048), 256, 0, stream>>>(gw, gs,  Wg, D_MODEL, wtot);
    dequant_w_kernel<<<(int)(wtot / 2048), 256, 0, stream>>>(uw, us,  Wu, D_MODEL, wtot);
    dequant_w_kernel<<<(int)(wtot / 2048), 256, 0, stream>>>(dw, dsc, Wd, D_FF,    wtot);
    cvt_x_kernel    <<<(int)(xtot / 2048), 256, 0, stream>>>(x, Xb, xtot);

    dim3 blk(256);
    dim3 g1(D_FF / 128, NTOK / 128);     // 86 x 64 = 5504 blocks
    dim3 g3(D_MODEL / 128, NTOK / 128);  // 32 x 64 = 2048 blocks

    // gate = Xb @ Wg^T  -> H (bf16)
    gemm_bt<0><<<g1, blk, 0, stream>>>(Xb, Wg, H, nullptr, NTOK, D_FF, D_MODEL);
    // up GEMM + fused h = silu(gate)*up -> H (in-place, same-index RMW)
    gemm_bt<1><<<g1, blk, 0, stream>>>(Xb, Wu, H, H, NTOK, D_FF, D_MODEL);
    // out = H @ Wd^T -> f32 d_out
    gemm_bt<2><<<g3, blk, 0, stream>>>(H, Wd, d_out, nullptr, NTOK, D_MODEL, D_FF);
}

// Round 2
// 2227.581 us; speedup vs baseline: 1.5973x; 1.5973x over previous
//
#include <hip/hip_runtime.h>

// ---------------------------------------------------------------------------
// SharedOnlyMLP: out = (silu(x@(gw*gs).T) * (x@(uw*us).T)) @ (dw*ds).T
// Round 2: 256x256-tile 8-phase pipelined bf16 MFMA GEMM (T1..T5 stack):
//   - BK=64 split into two K-halves [256][32] bf16, XOR-swizzled (both sides)
//   - 8 waves (2Mx4N), per-wave 128x64 output, acc[8][4] of 16x16x32 MFMA
//   - double-buffered 128 KiB dynamic LDS, global_load_lds width-16 staging
//   - counted s_waitcnt vmcnt(4) (never 0 in main loop), raw s_barrier,
//     s_setprio(1) around MFMA clusters, bijective XCD swizzle
// ---------------------------------------------------------------------------

typedef __attribute__((ext_vector_type(8))) __bf16 bf16x8;
typedef __attribute__((ext_vector_type(4))) float f32x4;
typedef __attribute__((ext_vector_type(8))) unsigned short ushort8;

#define D_MODEL 4096
#define D_FF    11008
#define NTOK    8192

static __device__ __forceinline__ unsigned short f32_to_bf16(float f) {
    union { float f; unsigned u; } v; v.f = f;
    unsigned r = v.u + 0x7fffu + ((v.u >> 16) & 1u);   // round-nearest-even
    return (unsigned short)(r >> 16);
}
static __device__ __forceinline__ float bf16_to_f32(unsigned short s) {
    union { unsigned u; float f; } v; v.u = ((unsigned)s) << 16;
    return v.f;
}

static __device__ __forceinline__ void gload_lds16(const void* g, void* l) {
    __builtin_amdgcn_global_load_lds(
        (const __attribute__((address_space(1))) void*)g,
        (__attribute__((address_space(3))) void*)l, 16, 0, 0);
}

// ---- weight dequant: int32 (int8 values) * s[row] -> bf16, 8 elems/thread ----
__global__ __launch_bounds__(256)
void dequant_w_kernel(const int* __restrict__ w, const float* __restrict__ s,
                      unsigned short* __restrict__ out, int cols, long long total)
{
    long long i = ((long long)blockIdx.x * 256 + threadIdx.x) * 8;
    if (i >= total) return;
    float sc = s[(int)(i / cols)];
    int4 w0 = *(const int4*)(w + i);
    int4 w1 = *(const int4*)(w + i + 4);
    ushort8 r;
    r[0] = f32_to_bf16((float)w0.x * sc);
    r[1] = f32_to_bf16((float)w0.y * sc);
    r[2] = f32_to_bf16((float)w0.z * sc);
    r[3] = f32_to_bf16((float)w0.w * sc);
    r[4] = f32_to_bf16((float)w1.x * sc);
    r[5] = f32_to_bf16((float)w1.y * sc);
    r[6] = f32_to_bf16((float)w1.z * sc);
    r[7] = f32_to_bf16((float)w1.w * sc);
    *(ushort8*)(out + i) = r;
}

// ---- x: f32 -> bf16, 8 elems/thread ----
__global__ __launch_bounds__(256)
void cvt_x_kernel(const float* __restrict__ x, unsigned short* __restrict__ out,
                  long long total)
{
    long long i = ((long long)blockIdx.x * 256 + threadIdx.x) * 8;
    if (i >= total) return;
    float4 a = *(const float4*)(x + i);
    float4 b = *(const float4*)(x + i + 4);
    ushort8 r;
    r[0] = f32_to_bf16(a.x); r[1] = f32_to_bf16(a.y);
    r[2] = f32_to_bf16(a.z); r[3] = f32_to_bf16(a.w);
    r[4] = f32_to_bf16(b.x); r[5] = f32_to_bf16(b.y);
    r[6] = f32_to_bf16(b.z); r[7] = f32_to_bf16(b.w);
    *(ushort8*)(out + i) = r;
}

// ---------------------------------------------------------------------------
// 256^2 8-phase GEMM: C[M][N] = A[M][K] @ B[N][K]^T
// LDS per buffer (64 KiB): A: 2 K-halves [256][32] bf16 (16 KiB each) at
// +0/+16384; B same at +32768/+49152. Two buffers (128 KiB total).
// Swizzle: within a 64-B row, byte ^= (((row>>1)&3)<<4); applied to the
// pre-swizzled global SOURCE column during staging and to the ds_read addr.
// ---------------------------------------------------------------------------
template<int MODE>
__global__ __launch_bounds__(512, 2)
void gemm256(const unsigned short* __restrict__ A,
             const unsigned short* __restrict__ B,
             void* __restrict__ C,
             const unsigned short* __restrict__ gateb,
             int M, int N, int K)
{
    extern __shared__ char smem[];
    const int tid = threadIdx.x;
    const int l   = tid & 63;
    const int w   = tid >> 6;
    const int wm  = w >> 2;          // 0..1
    const int wn  = w & 3;           // 0..3

    // bijective XCD swizzle (nwg % 8 == 0 for all our launches)
    const int nbx  = gridDim.x;
    const int nwg  = nbx * gridDim.y;
    const int orig = blockIdx.y * nbx + blockIdx.x;
    const int cpx  = nwg >> 3;
    const int swz  = (orig & 7) * cpx + (orig >> 3);
    const int bn = swz % nbx, bm = swz / nbx;
    const int m0 = bm * 256, n0 = bn * 256;

    // ---- staging lane geometry (pre-swizzled source column) ----
    const int st_r = w * 16 + (l >> 2);                    // row in 256-tile (instr 0)
    const int st_c = (((l & 3) ^ ((l >> 3) & 3)) << 3);    // elem col in 32-col K-half
    const unsigned short* gA = A + (size_t)(m0 + st_r) * K + st_c;
    const unsigned short* gB = B + (size_t)(n0 + st_r) * K + st_c;
    const size_t ld128 = (size_t)128 * K;

    // ---- ds_read lane offsets (swizzled) ----
    const int s4 = l >> 4;
    const int rA = wm * 128 + (l & 15);
    const int rB = wn * 64  + (l & 15);
    const int offA = rA * 64 + ((s4 << 4) ^ (((rA >> 1) & 3) << 4));
    const int offB = 32768 + rB * 64 + ((s4 << 4) ^ (((rB >> 1) & 3) << 4));

    const int T = K >> 6;            // K-tiles of 64

    f32x4 acc[8][4] = {};
    bf16x8 af[4], bfr[4];

#define SBAR()  __builtin_amdgcn_sched_barrier(0)
#define BAR()   __builtin_amdgcn_s_barrier()
#define VM4()   asm volatile("s_waitcnt vmcnt(4)" ::: "memory")
#define STAGE2(SRC, LOFF) do { \
    gload_lds16((SRC), smem + (LOFF) + (w << 10)); \
    gload_lds16((SRC) + ld128, smem + (LOFF) + 8192 + (w << 10)); } while (0)

#define MFMA16(MB) do { \
    _Pragma("unroll") \
    for (int mi_ = 0; mi_ < 4; ++mi_) { \
        _Pragma("unroll") \
        for (int ni_ = 0; ni_ < 4; ++ni_) { \
            acc[(MB) + mi_][ni_] = __builtin_amdgcn_mfma_f32_16x16x32_bf16( \
                af[mi_], bfr[ni_], acc[(MB) + mi_][ni_], 0, 0, 0); \
        } } } while (0)

// One K-tile = 4 phases: (h0,mi0-3)(h0,mi4-7)(h1,mi0-3)(h1,mi4-7).
// Stage stream during tile t: S(t+1): A_h0, B_h0, A_h1, B_h1 (2 loads each).
// vmcnt(4) at phase-2 end (protects this tile's h1) and phase-4 end
// (protects next tile's h0). Never 0 in the main loop.
#define TILE(DB, KTN) do { \
    const int CB = (DB) * 65536; \
    const int PB = ((DB) ^ 1) * 65536; \
    const unsigned short* sA = gA + ((size_t)(KTN) << 6); \
    const unsigned short* sB = gB + ((size_t)(KTN) << 6); \
    /* phase 1: h0, mi 0-3 (12 ds_reads) */ \
    af[0]  = *(const bf16x8*)(smem + CB + offA); \
    af[1]  = *(const bf16x8*)(smem + CB + offA + 1024); \
    af[2]  = *(const bf16x8*)(smem + CB + offA + 2048); \
    af[3]  = *(const bf16x8*)(smem + CB + offA + 3072); \
    bfr[0] = *(const bf16x8*)(smem + CB + offB); \
    bfr[1] = *(const bf16x8*)(smem + CB + offB + 1024); \
    bfr[2] = *(const bf16x8*)(smem + CB + offB + 2048); \
    bfr[3] = *(const bf16x8*)(smem + CB + offB + 3072); \
    STAGE2(sA, PB); \
    SBAR(); BAR(); \
    __builtin_amdgcn_s_setprio(1); MFMA16(0); __builtin_amdgcn_s_setprio(0); \
    SBAR(); BAR(); \
    /* phase 2: h0, mi 4-7 (4 ds_reads) */ \
    af[0] = *(const bf16x8*)(smem + CB + offA + 4096); \
    af[1] = *(const bf16x8*)(smem + CB + offA + 5120); \
    af[2] = *(const bf16x8*)(smem + CB + offA + 6144); \
    af[3] = *(const bf16x8*)(smem + CB + offA + 7168); \
    STAGE2(sB, PB + 32768); \
    SBAR(); BAR(); \
    __builtin_amdgcn_s_setprio(1); MFMA16(4); __builtin_amdgcn_s_setprio(0); \
    VM4(); SBAR(); BAR(); \
    /* phase 3: h1, mi 0-3 (12 ds_reads) */ \
    af[0]  = *(const bf16x8*)(smem + CB + 16384 + offA); \
    af[1]  = *(const bf16x8*)(smem + CB + 16384 + offA + 1024); \
    af[2]  = *(const bf16x8*)(smem + CB + 16384 + offA + 2048); \
    af[3]  = *(const bf16x8*)(smem + CB + 16384 + offA + 3072); \
    bfr[0] = *(const bf16x8*)(smem + CB + 16384 + offB); \
    bfr[1] = *(const bf16x8*)(smem + CB + 16384 + offB + 1024); \
    bfr[2] = *(const bf16x8*)(smem + CB + 16384 + offB + 2048); \
    bfr[3] = *(const bf16x8*)(smem + CB + 16384 + offB + 3072); \
    STAGE2(sA + 32, PB + 16384); \
    SBAR(); BAR(); \
    __builtin_amdgcn_s_setprio(1); MFMA16(0); __builtin_amdgcn_s_setprio(0); \
    SBAR(); BAR(); \
    /* phase 4: h1, mi 4-7 (4 ds_reads) */ \
    af[0] = *(const bf16x8*)(smem + CB + 16384 + offA + 4096); \
    af[1] = *(const bf16x8*)(smem + CB + 16384 + offA + 5120); \
    af[2] = *(const bf16x8*)(smem + CB + 16384 + offA + 6144); \
    af[3] = *(const bf16x8*)(smem + CB + 16384 + offA + 7168); \
    STAGE2(sB + 32, PB + 49152); \
    SBAR(); BAR(); \
    __builtin_amdgcn_s_setprio(1); MFMA16(4); __builtin_amdgcn_s_setprio(0); \
    VM4(); SBAR(); BAR(); \
} while (0)

    // prologue: stage tile 0 fully into buf0; wait its h0 (oldest 4 loads)
    STAGE2(gA,      0);
    STAGE2(gB,      32768);
    STAGE2(gA + 32, 16384);
    STAGE2(gB + 32, 49152);
    VM4(); SBAR(); BAR();

    const int T2 = T >> 1;           // T is even for all our K (64, 172)
    #pragma unroll 1
    for (int it = 0; it < T2; ++it) {
        const int t0 = it << 1;
        TILE(0, t0 + 1);
        const int kt2 = (t0 + 2 == T) ? 0 : (t0 + 2);   // last: redundant restage of tile 0
        TILE(1, kt2);
    }
    asm volatile("s_waitcnt vmcnt(0)" ::: "memory");    // drain dangling LDS writes

    // epilogue: C/D layout col=l&15, row=(l>>4)*4+q (m89-verified)
    const int er = (l >> 4) * 4;
    const int ec = l & 15;
    #pragma unroll
    for (int mi = 0; mi < 8; ++mi) {
        #pragma unroll
        for (int ni = 0; ni < 4; ++ni) {
            #pragma unroll
            for (int q = 0; q < 4; ++q) {
                int row = m0 + wm * 128 + mi * 16 + er + q;
                int col = n0 + wn * 64  + ni * 16 + ec;
                size_t idx = (size_t)row * N + col;
                float v = acc[mi][ni][q];
                if (MODE == 0) {
                    ((unsigned short*)C)[idx] = f32_to_bf16(v);
                } else if (MODE == 1) {
                    float g   = bf16_to_f32(gateb[idx]);
                    float sig = 1.0f / (1.0f + __expf(-g));
                    ((unsigned short*)C)[idx] = f32_to_bf16(g * sig * v);
                } else {
                    ((float*)C)[idx] = v;
                }
            }
        }
    }
#undef TILE
#undef MFMA16
#undef STAGE2
#undef VM4
#undef BAR
#undef SBAR
}

extern "C" void kernel_launch(void* const* d_in, const int* in_sizes, int n_in,
                              void* d_out, int out_size, void* d_ws, size_t ws_size,
                              hipStream_t stream)
{
    const float* x  = (const float*)d_in[0];
    const int*   gw = (const int*)  d_in[1];
    const float* gs = (const float*)d_in[2];
    const int*   uw = (const int*)  d_in[3];
    const float* us = (const float*)d_in[4];
    const int*   dw = (const int*)  d_in[5];
    const float* dsc= (const float*)d_in[6];

    // workspace layout
    char* ws = (char*)d_ws;
    unsigned short* Xb = (unsigned short*)ws;  ws += (size_t)NTOK  * D_MODEL * 2;
    unsigned short* Wg = (unsigned short*)ws;  ws += (size_t)D_FF  * D_MODEL * 2;
    unsigned short* Wu = (unsigned short*)ws;  ws += (size_t)D_FF  * D_MODEL * 2;
    unsigned short* Wd = (unsigned short*)ws;  ws += (size_t)D_MODEL * D_FF * 2;
    unsigned short* H  = (unsigned short*)ws;  // NTOK * D_FF bf16 (gate, then h)

    const long long wtot = (long long)D_FF * D_MODEL;
    const long long xtot = (long long)NTOK * D_MODEL;

    // allow 128 KiB dynamic LDS (idempotent host-side calls; not stream ops)
    hipFuncSetAttribute(reinterpret_cast<const void*>(gemm256<0>),
                        hipFuncAttributeMaxDynamicSharedMemorySize, 131072);
    hipFuncSetAttribute(reinterpret_cast<const void*>(gemm256<1>),
                        hipFuncAttributeMaxDynamicSharedMemorySize, 131072);
    hipFuncSetAttribute(reinterpret_cast<const void*>(gemm256<2>),
                        hipFuncAttributeMaxDynamicSharedMemorySize, 131072);

    dequant_w_kernel<<<(int)(wtot / 2048), 256, 0, stream>>>(gw, gs,  Wg, D_MODEL, wtot);
    dequant_w_kernel<<<(int)(wtot / 2048), 256, 0, stream>>>(uw, us,  Wu, D_MODEL, wtot);
    dequant_w_kernel<<<(int)(wtot / 2048), 256, 0, stream>>>(dw, dsc, Wd, D_FF,    wtot);
    cvt_x_kernel    <<<(int)(xtot / 2048), 256, 0, stream>>>(x, Xb, xtot);

    dim3 blk(512);
    dim3 g1(D_FF / 256, NTOK / 256);     // 43 x 32 = 1376 blocks (%8==0)
    dim3 g3(D_MODEL / 256, NTOK / 256);  // 16 x 32 = 512 blocks (%8==0)

    // gate = Xb @ Wg^T -> H (bf16)
    gemm256<0><<<g1, blk, 131072, stream>>>(Xb, Wg, H, nullptr, NTOK, D_FF, D_MODEL);
    // up GEMM + fused h = silu(gate)*up -> H (in-place, same-index RMW)
    gemm256<1><<<g1, blk, 131072, stream>>>(Xb, Wu, H, H, NTOK, D_FF, D_MODEL);
    // out = H @ Wd^T -> f32 d_out
    gemm256<2><<<g3, blk, 131072, stream>>>(H, Wd, d_out, nullptr, NTOK, D_MODEL, D_FF);
}